// Round 16
// baseline (399.620 us; speedup 1.0000x reference)
//
#include <hip/hip_runtime.h>

typedef __attribute__((ext_vector_type(8))) __bf16 bf16x8;
typedef __attribute__((ext_vector_type(4))) __bf16 bf16x4;
typedef __attribute__((ext_vector_type(4))) float f32x4;

#define DEV static __device__ __forceinline__

DEV float fast_rcp(float x) { return __builtin_amdgcn_rcpf(x); }
DEV float sigm(float x) { return fast_rcp(1.f + __expf(-x)); }
DEV float siluf(float x) { return x * sigm(x); }
DEV float softplusf(float x) { return x > 20.f ? x : __logf(1.f + __expf(x)); }

// ---------------- proj (96->192) MFMA GEMM + BN  ||  weight fp32->bf16 convert ----
__global__ __launch_bounds__(256) void k_proj_wcvt(
    const float* __restrict__ x, const float* __restrict__ pw,
    const float* __restrict__ pb, const float* __restrict__ bng,
    const float* __restrict__ bnb, const float* __restrict__ bnm,
    const float* __restrict__ bnv, float* __restrict__ v,
    const float* __restrict__ Win, const float* __restrict__ Wout,
    const float* __restrict__ Wx, __bf16* __restrict__ Wb)
{
  constexpr int SAP = 104;
  __shared__ __bf16 As[64 * SAP];
  __shared__ __bf16 Ws[64 * SAP];
  const int tid = threadIdx.x;
  const int bid = blockIdx.x;

  if (bid >= 294) {            // ---- wcvt part ----
    const int idx = (bid - 294) * 256 + tid;   // < 714240 exactly
    if (idx < 442368) Wb[idx] = (__bf16)Win[idx];
    else if (idx < 663552) Wb[idx] = (__bf16)Wout[idx - 442368];
    else Wb[idx] = (__bf16)Wx[idx - 663552];
    return;
  }

  const int r0 = (bid % 98) * 64;
  const int col0 = (bid / 98) * 64;
  const int b = r0 / 3136, l0 = r0 % 3136;
  const int lane = tid & 63, wv = tid >> 6;
  const int rh = wv >> 1, ch = wv & 1;
  const int lm = lane & 15, quad = lane >> 4;

#pragma unroll
  for (int it = 0; it < 6; ++it) {
    const int idx = tid + it * 256;
    const int c = idx >> 4, l4 = idx & 15;
    const float4 t = *(const float4*)(x + ((size_t)(b * 96 + c)) * 3136 + l0 + l4 * 4);
    As[(l4 * 4 + 0) * SAP + c] = (__bf16)t.x;
    As[(l4 * 4 + 1) * SAP + c] = (__bf16)t.y;
    As[(l4 * 4 + 2) * SAP + c] = (__bf16)t.z;
    As[(l4 * 4 + 3) * SAP + c] = (__bf16)t.w;
  }
#pragma unroll
  for (int it = 0; it < 6; ++it) {
    const int idx = tid + it * 256;
    const int wr = idx / 24, kc = (idx % 24) * 4;
    const float4 t = *(const float4*)(pw + (size_t)(col0 + wr) * 96 + kc);
    bf16x4 o;
    o[0] = (__bf16)t.x; o[1] = (__bf16)t.y; o[2] = (__bf16)t.z; o[3] = (__bf16)t.w;
    *(bf16x4*)(&Ws[wr * SAP + kc]) = o;
  }
  __syncthreads();

  f32x4 acc[2][2] = {};
#pragma unroll
  for (int ks = 0; ks < 3; ++ks) {
    const int kb = ks * 32 + quad * 8;
    bf16x8 a0 = *(const bf16x8*)(&As[(rh * 32 + lm) * SAP + kb]);
    bf16x8 a1 = *(const bf16x8*)(&As[(rh * 32 + 16 + lm) * SAP + kb]);
    bf16x8 b0 = *(const bf16x8*)(&Ws[(ch * 32 + lm) * SAP + kb]);
    bf16x8 b1 = *(const bf16x8*)(&Ws[(ch * 32 + 16 + lm) * SAP + kb]);
    acc[0][0] = __builtin_amdgcn_mfma_f32_16x16x32_bf16(a0, b0, acc[0][0], 0, 0, 0);
    acc[0][1] = __builtin_amdgcn_mfma_f32_16x16x32_bf16(a0, b1, acc[0][1], 0, 0, 0);
    acc[1][0] = __builtin_amdgcn_mfma_f32_16x16x32_bf16(a1, b0, acc[1][0], 0, 0, 0);
    acc[1][1] = __builtin_amdgcn_mfma_f32_16x16x32_bf16(a1, b1, acc[1][1], 0, 0, 0);
  }

#pragma unroll
  for (int ti = 0; ti < 2; ++ti)
#pragma unroll
    for (int tj = 0; tj < 2; ++tj) {
      const int gcol = col0 + ch * 32 + tj * 16 + lm;
      const float s = rsqrtf(bnv[gcol] + 1e-5f) * bng[gcol];
      const float sh = (pb[gcol] - bnm[gcol]) * s + bnb[gcol];
#pragma unroll
      for (int j = 0; j < 4; ++j) {
        const int grow = r0 + rh * 32 + ti * 16 + quad * 4 + j;
        v[(size_t)grow * 192 + gcol] = acc[ti][tj][j] * s + sh;
      }
    }
}

// ---------------- generic MFMA GEMM: O[r,e] = sum_d A[r,d]*W[e,d] ----------------
// AMODE: 1 = A bf16 plain; 2 = A fp32 + fused LN (K=192); 3 = A = LN(maxpool2(v)).
// EPI_XZ: x-half blocks (col0<384) run fused depthwise conv(K=4)+silu -> xiB bf16
//         (x-half of xz never hits global); z-half blocks write compact zb fp32.
constexpr int EPI_XZ = 0, EPI_G2 = 1, EPI_RES = 2, EPI_RES_SKIP = 3, EPI_OUT2 = 4;

template <int AMODE, int NT, int EPI>
__global__ __launch_bounds__(256) void k_gemm(
    const void* __restrict__ Ain, const __bf16* __restrict__ W,
    const float* __restrict__ bias, float* __restrict__ O,
    int M, int K, int Nvalid,
    float* __restrict__ dtlbuf, float* __restrict__ bcbuf,
    float* __restrict__ oflt,
    const float* __restrict__ lng, const float* __restrict__ lnb,
    const float* __restrict__ cw, const float* __restrict__ cb,
    __bf16* __restrict__ xiBout, float* __restrict__ zb,
    int Lseq)
{
  constexpr int SA = 200;
  constexpr int CT = (NT == 1) ? 2 : 4;
  __shared__ __bf16 As[64 * SA];
  __shared__ __bf16 Ws[64 * NT * SA];
  __shared__ __bf16 As2[(EPI == EPI_XZ) ? 3 * SA : 1];
  __shared__ float lnS[(AMODE >= 2) ? 384 : 1];
  const int tid = threadIdx.x;
  const int r0 = blockIdx.x * 64;
  const int col0 = blockIdx.y * (64 * NT);
  const int lane = tid & 63, wv = tid >> 6;
  const int rh = (NT == 1) ? (wv >> 1) : (wv & 1);
  const int ch = (NT == 1) ? (wv & 1) : (wv >> 1);
  const int lm = lane & 15, quad = lane >> 4;

  if constexpr (AMODE >= 2) {
    if (tid < 192) { lnS[tid] = lng[tid]; lnS[192 + tid] = lnb[tid]; }
    __syncthreads();
  }

  f32x4 acc[2][CT] = {};
  const int nkp = K / 192;
  for (int kp = 0; kp < nkp; ++kp) {
    if (kp) __syncthreads();
    // ---- stage A ----
    if constexpr (AMODE == 1) {
      const __bf16* Ab = (const __bf16*)Ain;
#pragma unroll
      for (int it = 0; it < 6; ++it) {
        const int idx = tid + it * 256;
        const int row = idx / 24, kc = (idx % 24) * 8;
        const int gr = min(r0 + row, M - 1);
        bf16x8 val = *(const bf16x8*)(Ab + (size_t)gr * K + kp * 192 + kc);
        *(bf16x8*)(&As[row * SA + kc]) = val;
      }
    } else {  // AMODE 2/3: fp32 row (direct or maxpooled) -> LN -> bf16
      const float* A = (const float*)Ain;
      // main 64 rows (4 threads/row) + 3 boundary rows (threads 0..11) for EPI_XZ
      const int nwork = (EPI == EPI_XZ && col0 < 384) ? 2 : 1;
      for (int w = 0; w < nwork; ++w) {
        int row, part, gr;
        __bf16* dst;
        if (w == 0) { row = tid >> 2; part = tid & 3; gr = min(r0 + row, M - 1); dst = &As[row * SA]; }
        else {
          if (tid >= 12) break;
          row = tid >> 2; part = tid & 3; gr = max(r0 - 3 + row, 0); dst = &As2[row * SA];
        }
        const int cbase = part * 48;
        float4 tv[12];
        if constexpr (AMODE == 2) {
#pragma unroll
          for (int j = 0; j < 12; ++j)
            tv[j] = *(const float4*)(A + (size_t)gr * 192 + cbase + j * 4);
        } else {  // maxpool2 of v: gr is pooled pixel index
          const int bb = gr / 784, l2 = gr % 784;
          const int h2 = l2 / 28, w2 = l2 % 28;
          const float* p0 = A + (size_t)(bb * 3136 + h2 * 112 + w2 * 2) * 192;
#pragma unroll
          for (int j = 0; j < 12; ++j) {
            const int cc = cbase + j * 4;
            const float4 a0 = *(const float4*)(p0 + cc);
            const float4 a1 = *(const float4*)(p0 + 192 + cc);
            const float4 a2 = *(const float4*)(p0 + 56 * 192 + cc);
            const float4 a3 = *(const float4*)(p0 + 57 * 192 + cc);
            tv[j].x = fmaxf(fmaxf(a0.x, a1.x), fmaxf(a2.x, a3.x));
            tv[j].y = fmaxf(fmaxf(a0.y, a1.y), fmaxf(a2.y, a3.y));
            tv[j].z = fmaxf(fmaxf(a0.z, a1.z), fmaxf(a2.z, a3.z));
            tv[j].w = fmaxf(fmaxf(a0.w, a1.w), fmaxf(a2.w, a3.w));
          }
        }
        float s = 0.f, sq = 0.f;
#pragma unroll
        for (int j = 0; j < 12; ++j) {
          s += tv[j].x + tv[j].y + tv[j].z + tv[j].w;
          sq += tv[j].x * tv[j].x + tv[j].y * tv[j].y + tv[j].z * tv[j].z + tv[j].w * tv[j].w;
        }
        s += __shfl_xor(s, 1); s += __shfl_xor(s, 2);
        sq += __shfl_xor(sq, 1); sq += __shfl_xor(sq, 2);
        const float mean = s * (1.f / 192.f);
        const float rstd = rsqrtf(sq * (1.f / 192.f) - mean * mean + 1e-5f);
#pragma unroll
        for (int j = 0; j < 12; ++j) {
          const int c = cbase + j * 4;
          bf16x4 o;
          o[0] = (__bf16)((tv[j].x - mean) * rstd * lnS[c + 0] + lnS[192 + c + 0]);
          o[1] = (__bf16)((tv[j].y - mean) * rstd * lnS[c + 1] + lnS[192 + c + 1]);
          o[2] = (__bf16)((tv[j].z - mean) * rstd * lnS[c + 2] + lnS[192 + c + 2]);
          o[3] = (__bf16)((tv[j].w - mean) * rstd * lnS[c + 3] + lnS[192 + c + 3]);
          *(bf16x4*)(dst + c) = o;
        }
      }
    }
    // ---- stage W (bf16) ----
#pragma unroll
    for (int it = 0; it < 6 * NT; ++it) {
      const int idx = tid + it * 256;
      const int wr = idx / 24, kc = (idx % 24) * 8;
      const int gw = col0 + wr;
      bf16x8 val = {};
      if (gw < Nvalid) val = *(const bf16x8*)(W + (size_t)gw * K + kp * 192 + kc);
      *(bf16x8*)(&Ws[wr * SA + kc]) = val;
    }
    __syncthreads();
    // ---- mfma ----
#pragma unroll
    for (int ks = 0; ks < 6; ++ks) {
      const int kb = ks * 32 + quad * 8;
      bf16x8 a0 = *(const bf16x8*)(&As[(rh * 32 + lm) * SA + kb]);
      bf16x8 a1 = *(const bf16x8*)(&As[(rh * 32 + 16 + lm) * SA + kb]);
#pragma unroll
      for (int tj = 0; tj < CT; ++tj) {
        bf16x8 bfr = *(const bf16x8*)(&Ws[(ch * (16 * CT) + tj * 16 + lm) * SA + kb]);
        acc[0][tj] = __builtin_amdgcn_mfma_f32_16x16x32_bf16(a0, bfr, acc[0][tj], 0, 0, 0);
        acc[1][tj] = __builtin_amdgcn_mfma_f32_16x16x32_bf16(a1, bfr, acc[1][tj], 0, 0, 0);
      }
    }
  }

  // ---- epilogue ----
  if constexpr (EPI == EPI_XZ) {
    if (col0 < 384) {
      // x-half: fused conv. 1) boundary xz rows r0-3..r0-1 via LDS dot.
      __syncthreads();
      float bval[2] = {0.f, 0.f};
#pragma unroll
      for (int jj = 0; jj < 2; ++jj) {
        const int j = tid + jj * 256;
        if (j < 384) {
          const int row3 = j >> 7, col = j & 127;
          float a = bias[col0 + col];
#pragma unroll
          for (int kk = 0; kk < 24; ++kk) {
            const bf16x8 a8 = *(const bf16x8*)(&As2[row3 * SA + kk * 8]);
            const bf16x8 w8 = *(const bf16x8*)(&Ws[col * SA + kk * 8]);
#pragma unroll
            for (int q = 0; q < 8; ++q) a += (float)a8[q] * (float)w8[q];
          }
          bval[jj] = a;
        }
      }
      __syncthreads();
      // 2) write XT (67 x 128, rows = xz r0-3..r0+63) into re-used Ws LDS.
      constexpr int XTP = 132;
      float* XT = (float*)Ws;
#pragma unroll
      for (int jj = 0; jj < 2; ++jj) {
        const int j = tid + jj * 256;
        if (j < 384) XT[(j >> 7) * XTP + (j & 127)] = bval[jj];
      }
#pragma unroll
      for (int ti = 0; ti < 2; ++ti)
#pragma unroll
        for (int tj = 0; tj < CT; ++tj) {
          const int colt = ch * (16 * CT) + tj * 16 + lm;
          const float bv = bias[col0 + colt];
#pragma unroll
          for (int j = 0; j < 4; ++j) {
            const int rowt = rh * 32 + ti * 16 + quad * 4 + j;
            XT[(rowt + 3) * XTP + colt] = acc[ti][tj][j] + bv;
          }
        }
      __syncthreads();
      // 3) conv K=4 + silu -> xiB
      const int c0 = tid & 31;
      const int rbase = (tid >> 5) * 8;
#pragma unroll
      for (int q = 0; q < 4; ++q) {
        const int col = c0 + 32 * q;
        const int e = col0 + col;
        const float4 w4 = *(const float4*)(cw + e * 4);
        const float cbe = cb[e];
#pragma unroll
        for (int rr = 0; rr < 8; ++rr) {
          const int lrow = rbase + rr;
          const int lg = r0 + lrow;
          const int lseq = lg % Lseq;
          float a = cbe;
#pragma unroll
          for (int k = 0; k < 4; ++k) {
            const float xv = (lseq - 3 + k >= 0) ? XT[(lrow + k) * XTP + col] : 0.f;
            a += w4[k] * ((const float*)&w4)[k] == 0.f ? 0.f : 0.f;  // (placeholder removed below)
            a += 0.f;
          }
          // recompute cleanly (compiler folds):
          a = cbe;
          if (lseq >= 3) {
            a += w4.x * XT[(lrow + 0) * XTP + col];
            a += w4.y * XT[(lrow + 1) * XTP + col];
            a += w4.z * XT[(lrow + 2) * XTP + col];
          } else {
            if (lseq >= 3) a += w4.x * XT[(lrow + 0) * XTP + col];
            if (lseq >= 2) a += w4.y * XT[(lrow + 1) * XTP + col];
            if (lseq >= 1) a += w4.z * XT[(lrow + 2) * XTP + col];
          }
          a += w4.w * XT[(lrow + 3) * XTP + col];
          if (lg < M) xiBout[(size_t)lg * 384 + e] = (__bf16)siluf(a);
        }
      }
    } else {
      // z-half: write compact zb fp32
#pragma unroll
      for (int ti = 0; ti < 2; ++ti)
#pragma unroll
        for (int tj = 0; tj < CT; ++tj) {
          const int colt = ch * (16 * CT) + tj * 16 + lm;
          const int gcol = col0 + colt;
          const float bv = bias[gcol];
#pragma unroll
          for (int j = 0; j < 4; ++j) {
            const int rowt = rh * 32 + ti * 16 + quad * 4 + j;
            const int grow = r0 + rowt;
            if (grow < M) zb[(size_t)grow * 384 + (gcol - 384)] = acc[ti][tj][j] + bv;
          }
        }
    }
  } else if constexpr (EPI == EPI_G2) {
    __shared__ float dtlS[64 * 12];
#pragma unroll
    for (int ti = 0; ti < 2; ++ti)
#pragma unroll
      for (int tj = 0; tj < CT; ++tj) {
        const int colt = ch * (16 * CT) + tj * 16 + lm;
#pragma unroll
        for (int j = 0; j < 4; ++j) {
          const int rowt = rh * 32 + ti * 16 + quad * 4 + j;
          const int grow = r0 + rowt;
          const float val = acc[ti][tj][j];
          if (colt < 12) dtlS[rowt * 12 + colt] = val;
          else if (colt < 44 && grow < M)
            bcbuf[(size_t)grow * 32 + (colt - 12)] = val;
        }
      }
    __syncthreads();
    for (int idx = tid; idx < 64 * 12; idx += 256) {
      const int grow = r0 + idx / 12;
      if (grow < M) dtlbuf[(size_t)grow * 12 + idx % 12] = dtlS[idx];
    }
  } else {
#pragma unroll
    for (int ti = 0; ti < 2; ++ti)
#pragma unroll
      for (int tj = 0; tj < CT; ++tj) {
        const int colt = ch * (16 * CT) + tj * 16 + lm;
        const int gcol = col0 + colt;
        const float bv = bias[gcol];
#pragma unroll
        for (int j = 0; j < 4; ++j) {
          const int rowt = rh * 32 + ti * 16 + quad * 4 + j;
          const int grow = r0 + rowt;
          if (grow >= M) continue;
          const float val = acc[ti][tj][j] + bv;
          if constexpr (EPI == EPI_RES) {
            O[(size_t)grow * 192 + gcol] += val;
          } else if constexpr (EPI == EPI_RES_SKIP) {
            const float nv = O[(size_t)grow * 192 + gcol] + val;
            O[(size_t)grow * 192 + gcol] = nv;
            const int b = grow / 3136, l = grow % 3136;
            oflt[b * 602112 + gcol * 3136 + l] = nv;
          } else {  // EPI_OUT2
            const int b = grow / 784, l = grow % 784;
            oflt[b * 150528 + gcol * 784 + l] = val;
          }
        }
      }
  }
}

// ======== chunked selective scan: 1 thread = 1 channel, 16 states in regs ========
constexpr int SC_LC = 28, SC_T = 7, SC_TN = 4;

DEV void compute_dts(const float* __restrict__ dtl, const float* __restrict__ Wdt,
                     const float* __restrict__ bdt, int rowbase, int e, int t,
                     float* dtlS, float* wdtS)
{
  for (int idx = t; idx < SC_LC * 12; idx += 128)
    dtlS[idx] = dtl[(size_t)(rowbase + idx / 12) * 12 + idx % 12];
#pragma unroll
  for (int r = 0; r < 12; ++r) wdtS[r * 128 + t] = Wdt[(size_t)e * 12 + r];
}

__global__ __launch_bounds__(128) void k_scan1(
    const float* __restrict__ dtl, const __bf16* __restrict__ xi,
    const float* __restrict__ bc, const float* __restrict__ Wdt,
    const float* __restrict__ bdt, const float* __restrict__ A_log,
    float* __restrict__ P, float* __restrict__ S, int Lseq, int NC)
{
  __shared__ float Bs[SC_LC * 16];
  __shared__ float dts[SC_LC * 128];
  __shared__ float dtlS[SC_LC * 12];
  __shared__ float wdtS[12 * 128];
  const int t = threadIdx.x;
  const int e = blockIdx.y * 128 + t;
  const int c = blockIdx.x % NC;
  const int b = blockIdx.x / NC;
  const int rowbase = b * Lseq + c * SC_LC;

  for (int idx = t; idx < SC_LC * 16; idx += 128) {
    const int l = idx >> 4, q = idx & 15;
    Bs[idx] = bc[(size_t)(rowbase + l) * 32 + q];
  }
  compute_dts(dtl, Wdt, bdt, rowbase, e, t, dtlS, wdtS);
  const float bdte = bdt[e];

  float An2[16];
  {
    const float4* a4 = (const float4*)(A_log + e * 16);
    float4 t0 = a4[0], t1 = a4[1], t2 = a4[2], t3 = a4[3];
    float tmp[16] = {t0.x, t0.y, t0.z, t0.w, t1.x, t1.y, t1.z, t1.w,
                     t2.x, t2.y, t2.z, t2.w, t3.x, t3.y, t3.z, t3.w};
#pragma unroll
    for (int n = 0; n < 16; ++n) An2[n] = -__expf(tmp[n]) * 1.44269504f;
  }
  __syncthreads();
  for (int l = 0; l < SC_LC; ++l) {
    float a = bdte;
#pragma unroll
    for (int r = 0; r < 12; ++r) a += dtlS[l * 12 + r] * wdtS[r * 128 + t];
    dts[l * 128 + t] = softplusf(a);
  }

  float h[16], ap[16];
#pragma unroll
  for (int n = 0; n < 16; ++n) { h[n] = 0.f; ap[n] = 1.f; }

  float xA[SC_T], xB[SC_T];
  auto LOADA = [&](int tt) {
#pragma unroll
    for (int j = 0; j < SC_T; ++j)
      xA[j] = (float)xi[(size_t)(rowbase + tt * SC_T + j) * 384 + e];
  };
  auto LOADB = [&](int tt) {
#pragma unroll
    for (int j = 0; j < SC_T; ++j)
      xB[j] = (float)xi[(size_t)(rowbase + tt * SC_T + j) * 384 + e];
  };
  auto COMP = [&](const float (&x8)[SC_T], int tt) {
#pragma unroll
    for (int j = 0; j < SC_T; ++j) {
      const int l = tt * SC_T + j;
      const float dtv = dts[l * 128 + t];
      const float u = dtv * x8[j];
      const float* Brow = &Bs[l * 16];
#pragma unroll
      for (int n = 0; n < 16; ++n) {
        const float a = __builtin_amdgcn_exp2f(dtv * An2[n]);
        h[n] = a * h[n] + u * Brow[n];
        ap[n] *= a;
      }
    }
  };

  LOADA(0);
#pragma unroll
  for (int tt = 0; tt < SC_TN; ++tt) {
    if (tt & 1) { if (tt + 1 < SC_TN) LOADA(tt + 1); COMP(xB, tt); }
    else        { if (tt + 1 < SC_TN) LOADB(tt + 1); COMP(xA, tt); }
  }

  const size_t o = ((size_t)(b * NC + c) * 384 + e) * 16;
#pragma unroll
  for (int q = 0; q < 4; ++q) {
    *(float4*)(P + o + q * 4) = make_float4(ap[q*4], ap[q*4+1], ap[q*4+2], ap[q*4+3]);
    *(float4*)(S + o + q * 4) = make_float4(h[q*4], h[q*4+1], h[q*4+2], h[q*4+3]);
  }
}

__global__ __launch_bounds__(256) void k_carry(
    const float* __restrict__ P, float* __restrict__ SH, int NC)
{
  const int tid = blockIdx.x * 256 + threadIdx.x;   // 12288
  const int b = tid / 6144, r = tid % 6144;
  size_t o = (size_t)b * NC * 6144 + r;
  float h = 0.f;
  for (int c0 = 0; c0 < NC; c0 += 4) {   // NC % 4 == 0 (112, 28)
    float p[4], s[4];
#pragma unroll
    for (int k = 0; k < 4; ++k) { p[k] = P[o + (size_t)k * 6144]; s[k] = SH[o + (size_t)k * 6144]; }
#pragma unroll
    for (int k = 0; k < 4; ++k) { SH[o + (size_t)k * 6144] = h; h = p[k] * h + s[k]; }
    o += (size_t)4 * 6144;
  }
}

__global__ __launch_bounds__(128) void k_scan2(
    const float* __restrict__ dtl, const __bf16* __restrict__ xi,
    const float* __restrict__ bc, const float* __restrict__ zb,
    const float* __restrict__ Wdt, const float* __restrict__ bdt,
    const float* __restrict__ A_log, const float* __restrict__ Dskip,
    const float* __restrict__ H0, __bf16* __restrict__ y, int Lseq, int NC)
{
  __shared__ float BCs[SC_LC * 32];
  __shared__ float dts[SC_LC * 128];
  __shared__ float dtlS[SC_LC * 12];
  __shared__ float wdtS[12 * 128];
  const int t = threadIdx.x;
  const int e = blockIdx.y * 128 + t;
  const int c = blockIdx.x % NC;
  const int b = blockIdx.x / NC;
  const int rowbase = b * Lseq + c * SC_LC;

  for (int idx = t; idx < SC_LC * 32; idx += 128)
    BCs[idx] = bc[(size_t)rowbase * 32 + idx];
  compute_dts(dtl, Wdt, bdt, rowbase, e, t, dtlS, wdtS);
  const float bdte = bdt[e];

  float An2[16];
  {
    const float4* a4 = (const float4*)(A_log + e * 16);
    float4 t0 = a4[0], t1 = a4[1], t2 = a4[2], t3 = a4[3];
    float tmp[16] = {t0.x, t0.y, t0.z, t0.w, t1.x, t1.y, t1.z, t1.w,
                     t2.x, t2.y, t2.z, t2.w, t3.x, t3.y, t3.z, t3.w};
#pragma unroll
    for (int n = 0; n < 16; ++n) An2[n] = -__expf(tmp[n]) * 1.44269504f;
  }
  float h[16];
  {
    const size_t o = ((size_t)(b * NC + c) * 384 + e) * 16;
    const float4* h4 = (const float4*)(H0 + o);
    float4 t0 = h4[0], t1 = h4[1], t2 = h4[2], t3 = h4[3];
    h[0]=t0.x; h[1]=t0.y; h[2]=t0.z; h[3]=t0.w;
    h[4]=t1.x; h[5]=t1.y; h[6]=t1.z; h[7]=t1.w;
    h[8]=t2.x; h[9]=t2.y; h[10]=t2.z; h[11]=t2.w;
    h[12]=t3.x; h[13]=t3.y; h[14]=t3.z; h[15]=t3.w;
  }
  __syncthreads();
  for (int l = 0; l < SC_LC; ++l) {
    float a = bdte;
#pragma unroll
    for (int r = 0; r < 12; ++r) a += dtlS[l * 12 + r] * wdtS[r * 128 + t];
    dts[l * 128 + t] = softplusf(a);
  }
  const float Dse = Dskip[e];

  float xA[SC_T], zA[SC_T], xB[SC_T], zB[SC_T];
  auto LOADA = [&](int tt) {
#pragma unroll
    for (int j = 0; j < SC_T; ++j) {
      const size_t r = (size_t)(rowbase + tt * SC_T + j);
      xA[j] = (float)xi[r * 384 + e];
      zA[j] = zb[r * 384 + e];
    }
  };
  auto LOADB = [&](int tt) {
#pragma unroll
    for (int j = 0; j < SC_T; ++j) {
      const size_t r = (size_t)(rowbase + tt * SC_T + j);
      xB[j] = (float)xi[r * 384 + e];
      zB[j] = zb[r * 384 + e];
    }
  };
  auto COMP = [&](const float (&x8)[SC_T], const float (&z8)[SC_T], int tt) {
#pragma unroll
    for (int j = 0; j < SC_T; ++j) {
      const int l = tt * SC_T + j;
      const float dtv = dts[l * 128 + t];
      const float xiv = x8[j];
      const float u = dtv * xiv;
      const float* Brow = &BCs[l * 32];
      const float* Crow = Brow + 16;
      float yv = 0.f;
#pragma unroll
      for (int n = 0; n < 16; ++n) {
        const float a = __builtin_amdgcn_exp2f(dtv * An2[n]);
        h[n] = a * h[n] + u * Brow[n];
        yv += h[n] * Crow[n];
      }
      y[(size_t)(rowbase + l) * 384 + e] = (__bf16)((yv + Dse * xiv) * siluf(z8[j]));
    }
  };

  LOADA(0);
#pragma unroll
  for (int tt = 0; tt < SC_TN; ++tt) {
    if (tt & 1) { if (tt + 1 < SC_TN) LOADA(tt + 1); COMP(xB, zB, tt); }
    else        { if (tt + 1 < SC_TN) LOADB(tt + 1); COMP(xA, zA, tt); }
  }
}

extern "C" void kernel_launch(void* const* d_in, const int* in_sizes, int n_in,
                              void* d_out, int out_size, void* d_ws, size_t ws_size,
                              hipStream_t stream)
{
  const float* x    = (const float*)d_in[0];
  const float* pw   = (const float*)d_in[1];
  const float* pb   = (const float*)d_in[2];
  const float* bng  = (const float*)d_in[3];
  const float* bnb  = (const float*)d_in[4];
  const float* bnm  = (const float*)d_in[5];
  const float* bnv  = (const float*)d_in[6];
  const float* lng  = (const float*)d_in[7];
  const float* lnb  = (const float*)d_in[8];
  const float* Win  = (const float*)d_in[9];
  const float* b_in = (const float*)d_in[10];
  const float* cw   = (const float*)d_in[11];
  const float* cb   = (const float*)d_in[12];
  const float* Wx   = (const float*)d_in[13];
  const float* Wdt  = (const float*)d_in[14];
  const float* bdt  = (const float*)d_in[15];
  const float* Alog = (const float*)d_in[16];
  const float* Dsk  = (const float*)d_in[17];
  const float* Wout = (const float*)d_in[18];
  const float* bout = (const float*)d_in[19];

  float* wsf = (float*)d_ws;
  float* v    = wsf;                     // 1204224
  float* zb   = v + 1204224;             // 2408448 (z-half, ld 384)
  float* dtlb = zb + 2408448;            // 75264
  float* bcb  = dtlb + 75264;            // 200704
  float* Sb   = bcb + 200704;            // 1376256 (S then H0)
  __bf16* xiB = (__bf16*)(Sb + 1376256); // 2408448 bf16
  __bf16* yB  = (__bf16*)(Sb + 1376256 + 1204224);   // 2408448 bf16
  __bf16* Wb  = (__bf16*)(Sb + 1376256 + 2408448);   // 714240 bf16

  float* out0 = (float*)d_out;
  float* out1 = out0 + 301056;
  float* Pbig = out0;                // 1376256 <= 1505280, consumed before out writes
  float* Psml = zb + 1204224;        // layer-2 zb uses 602112; 1204224+344064 fits

  k_proj_wcvt<<<3084, 256, 0, stream>>>(x, pw, pb, bng, bnb, bnm, bnv, v,
                                        Win, Wout, Wx, Wb);

  for (int i = 0; i < 3; ++i) {
    const int big = (i < 2) ? 1 : 0;
    const int Lseq = big ? 3136 : 784;
    const int M = 2 * Lseq;
    const int NC = Lseq / SC_LC;     // 112 big, 28 small
    const int MB = (M + 63) / 64;    // 98 big, 25 small
    const float* lng_i = lng + i * 192;
    const float* lnb_i = lnb + i * 192;
    const float* bin_i = b_in + i * 768;
    const float* cw_i  = cw + i * 384 * 4;
    const float* cb_i  = cb + i * 384;
    const float* Wdt_i = Wdt + i * 384 * 12;
    const float* bdt_i = bdt + i * 384;
    const float* Al_i  = Alog + i * 384 * 16;
    const float* Ds_i  = Dsk + i * 384;
    const float* bo_i  = bout + i * 192;
    const __bf16* Winb_i  = Wb + i * 147456;
    const __bf16* Woutb_i = Wb + 442368 + i * 73728;
    const __bf16* Wxb_i   = Wb + 663552 + i * 16896;
    float* Pb = big ? Pbig : Psml;

    // xz GEMM with fused conv (x-half -> xiB) and z-half -> zb
    if (big)
      k_gemm<2, 2, EPI_XZ><<<dim3(MB, 6), 256, 0, stream>>>(
          v, Winb_i, bin_i, nullptr, M, 192, 768,
          nullptr, nullptr, nullptr, lng_i, lnb_i,
          cw_i, cb_i, xiB, zb, Lseq);
    else
      k_gemm<3, 2, EPI_XZ><<<dim3(MB, 6), 256, 0, stream>>>(
          v, Winb_i, bin_i, nullptr, M, 192, 768,
          nullptr, nullptr, nullptr, lng_i, lnb_i,
          cw_i, cb_i, xiB, zb, Lseq);
    // proj (44 cols): writes dtl (M x 12) + bc (M x 32)
    k_gemm<1, 1, EPI_G2><<<dim3(MB, 1), 256, 0, stream>>>(
        xiB, Wxb_i, nullptr, nullptr, M, 384, 44,
        dtlb, bcb, nullptr, nullptr, nullptr,
        nullptr, nullptr, nullptr, nullptr, Lseq);
    k_scan1<<<dim3(2 * NC, 3), 128, 0, stream>>>(
        dtlb, xiB, bcb, Wdt_i, bdt_i, Al_i, Pb, Sb, Lseq, NC);
    k_carry<<<48, 256, 0, stream>>>(Pb, Sb, NC);
    k_scan2<<<dim3(2 * NC, 3), 128, 0, stream>>>(
        dtlb, xiB, bcb, zb, Wdt_i, bdt_i, Al_i, Ds_i, Sb, yB, Lseq, NC);
    if (i == 0)
      k_gemm<1, 1, EPI_RES><<<dim3(MB, 3), 256, 0, stream>>>(
          yB, Woutb_i, bo_i, v, M, 384, 192,
          nullptr, nullptr, nullptr, nullptr, nullptr,
          nullptr, nullptr, nullptr, nullptr, Lseq);
    else if (i == 1)
      k_gemm<1, 1, EPI_RES_SKIP><<<dim3(MB, 3), 256, 0, stream>>>(
          yB, Woutb_i, bo_i, v, M, 384, 192,
          nullptr, nullptr, out1, nullptr, nullptr,
          nullptr, nullptr, nullptr, nullptr, Lseq);
    else
      k_gemm<1, 1, EPI_OUT2><<<dim3(MB, 3), 256, 0, stream>>>(
          yB, Woutb_i, bo_i, v, M, 384, 192,
          nullptr, nullptr, out0, nullptr, nullptr,
          nullptr, nullptr, nullptr, nullptr, Lseq);
  }
}

// Round 17
// 383.564 us; speedup vs baseline: 1.0419x; 1.0419x over previous
//
#include <hip/hip_runtime.h>

typedef __attribute__((ext_vector_type(8))) __bf16 bf16x8;
typedef __attribute__((ext_vector_type(4))) __bf16 bf16x4;
typedef __attribute__((ext_vector_type(4))) float f32x4;

#define DEV static __device__ __forceinline__

DEV float fast_rcp(float x) { return __builtin_amdgcn_rcpf(x); }
DEV float sigm(float x) { return fast_rcp(1.f + __expf(-x)); }
DEV float siluf(float x) { return x * sigm(x); }
DEV float softplusf(float x) { return x > 20.f ? x : __logf(1.f + __expf(x)); }

// ---------------- proj (96->192) MFMA GEMM + BN  ||  weight fp32->bf16 convert ----
__global__ __launch_bounds__(256) void k_proj_wcvt(
    const float* __restrict__ x, const float* __restrict__ pw,
    const float* __restrict__ pb, const float* __restrict__ bng,
    const float* __restrict__ bnb, const float* __restrict__ bnm,
    const float* __restrict__ bnv, float* __restrict__ v,
    const float* __restrict__ Win, const float* __restrict__ Wout,
    const float* __restrict__ Wx, __bf16* __restrict__ Wb)
{
  constexpr int SAP = 104;
  __shared__ __bf16 As[64 * SAP];
  __shared__ __bf16 Ws[64 * SAP];
  const int tid = threadIdx.x;
  const int bid = blockIdx.x;

  if (bid >= 294) {            // ---- wcvt part ----
    const int idx = (bid - 294) * 256 + tid;   // < 714240 exactly
    if (idx < 442368) Wb[idx] = (__bf16)Win[idx];
    else if (idx < 663552) Wb[idx] = (__bf16)Wout[idx - 442368];
    else Wb[idx] = (__bf16)Wx[idx - 663552];
    return;
  }

  const int r0 = (bid % 98) * 64;
  const int col0 = (bid / 98) * 64;
  const int b = r0 / 3136, l0 = r0 % 3136;
  const int lane = tid & 63, wv = tid >> 6;
  const int rh = wv >> 1, ch = wv & 1;
  const int lm = lane & 15, quad = lane >> 4;

#pragma unroll
  for (int it = 0; it < 6; ++it) {
    const int idx = tid + it * 256;
    const int c = idx >> 4, l4 = idx & 15;
    const float4 t = *(const float4*)(x + ((size_t)(b * 96 + c)) * 3136 + l0 + l4 * 4);
    As[(l4 * 4 + 0) * SAP + c] = (__bf16)t.x;
    As[(l4 * 4 + 1) * SAP + c] = (__bf16)t.y;
    As[(l4 * 4 + 2) * SAP + c] = (__bf16)t.z;
    As[(l4 * 4 + 3) * SAP + c] = (__bf16)t.w;
  }
#pragma unroll
  for (int it = 0; it < 6; ++it) {
    const int idx = tid + it * 256;
    const int wr = idx / 24, kc = (idx % 24) * 4;
    const float4 t = *(const float4*)(pw + (size_t)(col0 + wr) * 96 + kc);
    bf16x4 o;
    o[0] = (__bf16)t.x; o[1] = (__bf16)t.y; o[2] = (__bf16)t.z; o[3] = (__bf16)t.w;
    *(bf16x4*)(&Ws[wr * SAP + kc]) = o;
  }
  __syncthreads();

  f32x4 acc[2][2] = {};
#pragma unroll
  for (int ks = 0; ks < 3; ++ks) {
    const int kb = ks * 32 + quad * 8;
    bf16x8 a0 = *(const bf16x8*)(&As[(rh * 32 + lm) * SAP + kb]);
    bf16x8 a1 = *(const bf16x8*)(&As[(rh * 32 + 16 + lm) * SAP + kb]);
    bf16x8 b0 = *(const bf16x8*)(&Ws[(ch * 32 + lm) * SAP + kb]);
    bf16x8 b1 = *(const bf16x8*)(&Ws[(ch * 32 + 16 + lm) * SAP + kb]);
    acc[0][0] = __builtin_amdgcn_mfma_f32_16x16x32_bf16(a0, b0, acc[0][0], 0, 0, 0);
    acc[0][1] = __builtin_amdgcn_mfma_f32_16x16x32_bf16(a0, b1, acc[0][1], 0, 0, 0);
    acc[1][0] = __builtin_amdgcn_mfma_f32_16x16x32_bf16(a1, b0, acc[1][0], 0, 0, 0);
    acc[1][1] = __builtin_amdgcn_mfma_f32_16x16x32_bf16(a1, b1, acc[1][1], 0, 0, 0);
  }

#pragma unroll
  for (int ti = 0; ti < 2; ++ti)
#pragma unroll
    for (int tj = 0; tj < 2; ++tj) {
      const int gcol = col0 + ch * 32 + tj * 16 + lm;
      const float s = rsqrtf(bnv[gcol] + 1e-5f) * bng[gcol];
      const float sh = (pb[gcol] - bnm[gcol]) * s + bnb[gcol];
#pragma unroll
      for (int j = 0; j < 4; ++j) {
        const int grow = r0 + rh * 32 + ti * 16 + quad * 4 + j;
        v[(size_t)grow * 192 + gcol] = acc[ti][tj][j] * s + sh;
      }
    }
}

// ---------------- depthwise causal conv K=4 + silu, 8 outputs/thread -> xiB bf16 ----
__global__ __launch_bounds__(256) void k_conv(
    const float* __restrict__ xz, __bf16* __restrict__ xiB,
    const float* __restrict__ cw, const float* __restrict__ cb,
    int Lseq, int nthreads)
{
  const int idx = blockIdx.x * 256 + threadIdx.x;
  if (idx >= nthreads) return;
  const int e = idx % 384;
  const int seg = idx / 384;
  const int nseg = Lseq / 8;
  const int b = seg / nseg;
  const int l0 = (seg % nseg) * 8;
  const float4 w4 = *(const float4*)(cw + e * 4);
  const float bv = cb[e];
  float xv[11];
#pragma unroll
  for (int k = 0; k < 11; ++k) {
    const int l = l0 - 3 + k;
    xv[k] = (l >= 0) ? xz[(size_t)(b * Lseq + l) * 768 + e] : 0.f;
  }
#pragma unroll
  for (int j = 0; j < 8; ++j) {
    const float a = bv + xv[j] * w4.x + xv[j + 1] * w4.y + xv[j + 2] * w4.z + xv[j + 3] * w4.w;
    xiB[(size_t)(b * Lseq + l0 + j) * 384 + e] = (__bf16)siluf(a);
  }
}

// ---------------- generic MFMA GEMM: O[r,e] = sum_d A[r,d]*W[e,d] ----------------
// AMODE: 1 = A bf16 plain; 2 = A fp32 + fused LN (K=192); 3 = A = LN(maxpool2(v)).
constexpr int EPI_XZ = 0, EPI_G2 = 1, EPI_RES = 2, EPI_RES_SKIP = 3, EPI_OUT2 = 4;

template <int AMODE, int NT, int EPI>
__global__ __launch_bounds__(256) void k_gemm(
    const void* __restrict__ Ain, const __bf16* __restrict__ W,
    const float* __restrict__ bias, float* __restrict__ O,
    int M, int K, int Nvalid,
    float* __restrict__ dtlbuf, float* __restrict__ bcbuf,
    float* __restrict__ oflt,
    const float* __restrict__ lng, const float* __restrict__ lnb,
    int Lseq)
{
  constexpr int SA = 200;
  constexpr int CT = (NT == 1) ? 2 : 4;
  __shared__ __bf16 As[64 * SA];
  __shared__ __bf16 Ws[64 * NT * SA];
  __shared__ float lnS[(AMODE >= 2) ? 384 : 1];
  const int tid = threadIdx.x;
  const int r0 = blockIdx.x * 64;
  const int col0 = blockIdx.y * (64 * NT);
  const int lane = tid & 63, wv = tid >> 6;
  const int rh = (NT == 1) ? (wv >> 1) : (wv & 1);
  const int ch = (NT == 1) ? (wv & 1) : (wv >> 1);
  const int lm = lane & 15, quad = lane >> 4;

  if constexpr (AMODE >= 2) {
    if (tid < 192) { lnS[tid] = lng[tid]; lnS[192 + tid] = lnb[tid]; }
    __syncthreads();
  }

  f32x4 acc[2][CT] = {};
  const int nkp = K / 192;
  for (int kp = 0; kp < nkp; ++kp) {
    if (kp) __syncthreads();
    // ---- stage A ----
    if constexpr (AMODE == 1) {
      const __bf16* Ab = (const __bf16*)Ain;
#pragma unroll
      for (int it = 0; it < 6; ++it) {
        const int idx = tid + it * 256;
        const int row = idx / 24, kc = (idx % 24) * 8;
        const int gr = min(r0 + row, M - 1);   // clamp: padding rows read valid mem
        bf16x8 val = *(const bf16x8*)(Ab + (size_t)gr * K + kp * 192 + kc);
        *(bf16x8*)(&As[row * SA + kc]) = val;
      }
    } else {  // AMODE 2 or 3: build fp32 row then LN -> bf16
      const float* A = (const float*)Ain;
      const int row = tid >> 2, part = tid & 3;
      const int gr = min(r0 + row, M - 1);
      const int cbase = part * 48;
      float4 tv[12];
      if constexpr (AMODE == 2) {
#pragma unroll
        for (int j = 0; j < 12; ++j)
          tv[j] = *(const float4*)(A + (size_t)gr * 192 + cbase + j * 4);
      } else {  // AMODE == 3: maxpool2 of v (B,3136,192); gr is pooled pixel index
        const int bb = gr / 784, l2 = gr % 784;
        const int h2 = l2 / 28, w2 = l2 % 28;
        const float* p0 = A + (size_t)(bb * 3136 + h2 * 112 + w2 * 2) * 192;
#pragma unroll
        for (int j = 0; j < 12; ++j) {
          const int cc = cbase + j * 4;
          const float4 a0 = *(const float4*)(p0 + cc);
          const float4 a1 = *(const float4*)(p0 + 192 + cc);
          const float4 a2 = *(const float4*)(p0 + 56 * 192 + cc);
          const float4 a3 = *(const float4*)(p0 + 57 * 192 + cc);
          tv[j].x = fmaxf(fmaxf(a0.x, a1.x), fmaxf(a2.x, a3.x));
          tv[j].y = fmaxf(fmaxf(a0.y, a1.y), fmaxf(a2.y, a3.y));
          tv[j].z = fmaxf(fmaxf(a0.z, a1.z), fmaxf(a2.z, a3.z));
          tv[j].w = fmaxf(fmaxf(a0.w, a1.w), fmaxf(a2.w, a3.w));
        }
      }
      float s = 0.f, sq = 0.f;
#pragma unroll
      for (int j = 0; j < 12; ++j) {
        s += tv[j].x + tv[j].y + tv[j].z + tv[j].w;
        sq += tv[j].x * tv[j].x + tv[j].y * tv[j].y + tv[j].z * tv[j].z + tv[j].w * tv[j].w;
      }
      s += __shfl_xor(s, 1); s += __shfl_xor(s, 2);
      sq += __shfl_xor(sq, 1); sq += __shfl_xor(sq, 2);
      const float mean = s * (1.f / 192.f);
      const float rstd = rsqrtf(sq * (1.f / 192.f) - mean * mean + 1e-5f);
#pragma unroll
      for (int j = 0; j < 12; ++j) {
        const int c = cbase + j * 4;
        bf16x4 o;
        o[0] = (__bf16)((tv[j].x - mean) * rstd * lnS[c + 0] + lnS[192 + c + 0]);
        o[1] = (__bf16)((tv[j].y - mean) * rstd * lnS[c + 1] + lnS[192 + c + 1]);
        o[2] = (__bf16)((tv[j].z - mean) * rstd * lnS[c + 2] + lnS[192 + c + 2]);
        o[3] = (__bf16)((tv[j].w - mean) * rstd * lnS[c + 3] + lnS[192 + c + 3]);
        *(bf16x4*)(&As[row * SA + c]) = o;
      }
    }
    // ---- stage W (bf16) ----
#pragma unroll
    for (int it = 0; it < 6 * NT; ++it) {
      const int idx = tid + it * 256;
      const int wr = idx / 24, kc = (idx % 24) * 8;
      const int gw = col0 + wr;
      bf16x8 val = {};
      if (gw < Nvalid) val = *(const bf16x8*)(W + (size_t)gw * K + kp * 192 + kc);
      *(bf16x8*)(&Ws[wr * SA + kc]) = val;
    }
    __syncthreads();
    // ---- mfma ----
#pragma unroll
    for (int ks = 0; ks < 6; ++ks) {
      const int kb = ks * 32 + quad * 8;
      bf16x8 a0 = *(const bf16x8*)(&As[(rh * 32 + lm) * SA + kb]);
      bf16x8 a1 = *(const bf16x8*)(&As[(rh * 32 + 16 + lm) * SA + kb]);
#pragma unroll
      for (int tj = 0; tj < CT; ++tj) {
        bf16x8 bfr = *(const bf16x8*)(&Ws[(ch * (16 * CT) + tj * 16 + lm) * SA + kb]);
        acc[0][tj] = __builtin_amdgcn_mfma_f32_16x16x32_bf16(a0, bfr, acc[0][tj], 0, 0, 0);
        acc[1][tj] = __builtin_amdgcn_mfma_f32_16x16x32_bf16(a1, bfr, acc[1][tj], 0, 0, 0);
      }
    }
  }

  // ---- epilogue ----
  if constexpr (EPI == EPI_G2) {
    __shared__ float dtlS[64 * 12];
#pragma unroll
    for (int ti = 0; ti < 2; ++ti)
#pragma unroll
      for (int tj = 0; tj < CT; ++tj) {
        const int colt = ch * (16 * CT) + tj * 16 + lm;
#pragma unroll
        for (int j = 0; j < 4; ++j) {
          const int rowt = rh * 32 + ti * 16 + quad * 4 + j;
          const int grow = r0 + rowt;
          const float val = acc[ti][tj][j];
          if (colt < 12) dtlS[rowt * 12 + colt] = val;
          else if (colt < 44 && grow < M)
            bcbuf[(size_t)grow * 32 + (colt - 12)] = val;
        }
      }
    __syncthreads();
    for (int idx = tid; idx < 64 * 12; idx += 256) {
      const int grow = r0 + idx / 12;
      if (grow < M) dtlbuf[(size_t)grow * 12 + idx % 12] = dtlS[idx];
    }
  } else {
#pragma unroll
    for (int ti = 0; ti < 2; ++ti)
#pragma unroll
      for (int tj = 0; tj < CT; ++tj) {
        const int colt = ch * (16 * CT) + tj * 16 + lm;
        const int gcol = col0 + colt;
        const float bv = bias[gcol];
#pragma unroll
        for (int j = 0; j < 4; ++j) {
          const int rowt = rh * 32 + ti * 16 + quad * 4 + j;
          const int grow = r0 + rowt;
          if (grow >= M) continue;
          const float val = acc[ti][tj][j] + bv;
          if constexpr (EPI == EPI_XZ) {
            O[(size_t)grow * 768 + gcol] = val;
          } else if constexpr (EPI == EPI_RES) {
            O[(size_t)grow * 192 + gcol] += val;
          } else if constexpr (EPI == EPI_RES_SKIP) {
            const float nv = O[(size_t)grow * 192 + gcol] + val;
            O[(size_t)grow * 192 + gcol] = nv;
            const int b = grow / 3136, l = grow % 3136;
            oflt[b * 602112 + gcol * 3136 + l] = nv;
          } else {  // EPI_OUT2
            const int b = grow / 784, l = grow % 784;
            oflt[b * 150528 + gcol * 784 + l] = val;
          }
        }
      }
  }
}

// ======== chunked selective scan: 1 thread = 1 channel, 16 states in regs ========
// LC=14 -> 1344 blocks big-layer (2x R15's TLP); dt computed in-kernel from dtl.
constexpr int SC_LC = 14, SC_T = 7, SC_TN = 2;

DEV void compute_dts(const float* __restrict__ dtl, const float* __restrict__ Wdt,
                     const float* __restrict__ bdt, int rowbase, int e, int t,
                     float* dtlS, float* wdtS)
{
  for (int idx = t; idx < SC_LC * 12; idx += 128)
    dtlS[idx] = dtl[(size_t)(rowbase + idx / 12) * 12 + idx % 12];
#pragma unroll
  for (int r = 0; r < 12; ++r) wdtS[r * 128 + t] = Wdt[(size_t)e * 12 + r];
}

__global__ __launch_bounds__(128) void k_scan1(
    const float* __restrict__ dtl, const __bf16* __restrict__ xi,
    const float* __restrict__ bc, const float* __restrict__ Wdt,
    const float* __restrict__ bdt, const float* __restrict__ A_log,
    float* __restrict__ P, float* __restrict__ S, int Lseq, int NC)
{
  __shared__ float Bs[SC_LC * 16];
  __shared__ float dts[SC_LC * 128];
  __shared__ float dtlS[SC_LC * 12];
  __shared__ float wdtS[12 * 128];
  const int t = threadIdx.x;
  const int e = blockIdx.y * 128 + t;
  const int c = blockIdx.x % NC;
  const int b = blockIdx.x / NC;
  const int rowbase = b * Lseq + c * SC_LC;

  for (int idx = t; idx < SC_LC * 16; idx += 128) {
    const int l = idx >> 4, q = idx & 15;
    Bs[idx] = bc[(size_t)(rowbase + l) * 32 + q];
  }
  compute_dts(dtl, Wdt, bdt, rowbase, e, t, dtlS, wdtS);
  const float bdte = bdt[e];

  float An2[16];
  {
    const float4* a4 = (const float4*)(A_log + e * 16);
    float4 t0 = a4[0], t1 = a4[1], t2 = a4[2], t3 = a4[3];
    float tmp[16] = {t0.x, t0.y, t0.z, t0.w, t1.x, t1.y, t1.z, t1.w,
                     t2.x, t2.y, t2.z, t2.w, t3.x, t3.y, t3.z, t3.w};
#pragma unroll
    for (int n = 0; n < 16; ++n) An2[n] = -__expf(tmp[n]) * 1.44269504f;
  }
  __syncthreads();
  for (int l = 0; l < SC_LC; ++l) {
    float a = bdte;
#pragma unroll
    for (int r = 0; r < 12; ++r) a += dtlS[l * 12 + r] * wdtS[r * 128 + t];
    dts[l * 128 + t] = softplusf(a);
  }

  float h[16], ap[16];
#pragma unroll
  for (int n = 0; n < 16; ++n) { h[n] = 0.f; ap[n] = 1.f; }

  float xA[SC_T], xB[SC_T];
  auto LOADA = [&](int tt) {
#pragma unroll
    for (int j = 0; j < SC_T; ++j)
      xA[j] = (float)xi[(size_t)(rowbase + tt * SC_T + j) * 384 + e];
  };
  auto LOADB = [&](int tt) {
#pragma unroll
    for (int j = 0; j < SC_T; ++j)
      xB[j] = (float)xi[(size_t)(rowbase + tt * SC_T + j) * 384 + e];
  };
  auto COMP = [&](const float (&x8)[SC_T], int tt) {
#pragma unroll
    for (int j = 0; j < SC_T; ++j) {
      const int l = tt * SC_T + j;
      const float dtv = dts[l * 128 + t];
      const float u = dtv * x8[j];
      const float* Brow = &Bs[l * 16];
#pragma unroll
      for (int n = 0; n < 16; ++n) {
        const float a = __builtin_amdgcn_exp2f(dtv * An2[n]);
        h[n] = a * h[n] + u * Brow[n];
        ap[n] *= a;
      }
    }
  };

  LOADA(0);
#pragma unroll
  for (int tt = 0; tt < SC_TN; ++tt) {
    if (tt & 1) { if (tt + 1 < SC_TN) LOADA(tt + 1); COMP(xB, tt); }
    else        { if (tt + 1 < SC_TN) LOADB(tt + 1); COMP(xA, tt); }
  }

  const size_t o = ((size_t)(b * NC + c) * 384 + e) * 16;
#pragma unroll
  for (int q = 0; q < 4; ++q) {
    *(float4*)(P + o + q * 4) = make_float4(ap[q*4], ap[q*4+1], ap[q*4+2], ap[q*4+3]);
    *(float4*)(S + o + q * 4) = make_float4(h[q*4], h[q*4+1], h[q*4+2], h[q*4+3]);
  }
}

// carry: prefix-fold chunk (P,S) -> H0 in-place over S; 4-deep batched loads
__global__ __launch_bounds__(256) void k_carry(
    const float* __restrict__ P, float* __restrict__ SH, int NC)
{
  const int tid = blockIdx.x * 256 + threadIdx.x;   // 12288
  const int b = tid / 6144, r = tid % 6144;
  size_t o = (size_t)b * NC * 6144 + r;
  float h = 0.f;
  for (int c0 = 0; c0 < NC; c0 += 4) {   // NC % 4 == 0 (224, 56)
    float p[4], s[4];
#pragma unroll
    for (int k = 0; k < 4; ++k) { p[k] = P[o + (size_t)k * 6144]; s[k] = SH[o + (size_t)k * 6144]; }
#pragma unroll
    for (int k = 0; k < 4; ++k) { SH[o + (size_t)k * 6144] = h; h = p[k] * h + s[k]; }
    o += (size_t)4 * 6144;
  }
}

// scan2: init from H0, recompute chunk, emit gated y (bf16)
__global__ __launch_bounds__(128) void k_scan2(
    const float* __restrict__ dtl, const __bf16* __restrict__ xi,
    const float* __restrict__ bc, const float* __restrict__ xz,
    const float* __restrict__ Wdt, const float* __restrict__ bdt,
    const float* __restrict__ A_log, const float* __restrict__ Dskip,
    const float* __restrict__ H0, __bf16* __restrict__ y, int Lseq, int NC)
{
  __shared__ float BCs[SC_LC * 32];
  __shared__ float dts[SC_LC * 128];
  __shared__ float dtlS[SC_LC * 12];
  __shared__ float wdtS[12 * 128];
  const int t = threadIdx.x;
  const int e = blockIdx.y * 128 + t;
  const int c = blockIdx.x % NC;
  const int b = blockIdx.x / NC;
  const int rowbase = b * Lseq + c * SC_LC;

  for (int idx = t; idx < SC_LC * 32; idx += 128)
    BCs[idx] = bc[(size_t)rowbase * 32 + idx];
  compute_dts(dtl, Wdt, bdt, rowbase, e, t, dtlS, wdtS);
  const float bdte = bdt[e];

  float An2[16];
  {
    const float4* a4 = (const float4*)(A_log + e * 16);
    float4 t0 = a4[0], t1 = a4[1], t2 = a4[2], t3 = a4[3];
    float tmp[16] = {t0.x, t0.y, t0.z, t0.w, t1.x, t1.y, t1.z, t1.w,
                     t2.x, t2.y, t2.z, t2.w, t3.x, t3.y, t3.z, t3.w};
#pragma unroll
    for (int n = 0; n < 16; ++n) An2[n] = -__expf(tmp[n]) * 1.44269504f;
  }
  float h[16];
  {
    const size_t o = ((size_t)(b * NC + c) * 384 + e) * 16;
    const float4* h4 = (const float4*)(H0 + o);
    float4 t0 = h4[0], t1 = h4[1], t2 = h4[2], t3 = h4[3];
    h[0]=t0.x; h[1]=t0.y; h[2]=t0.z; h[3]=t0.w;
    h[4]=t1.x; h[5]=t1.y; h[6]=t1.z; h[7]=t1.w;
    h[8]=t2.x; h[9]=t2.y; h[10]=t2.z; h[11]=t2.w;
    h[12]=t3.x; h[13]=t3.y; h[14]=t3.z; h[15]=t3.w;
  }
  __syncthreads();
  for (int l = 0; l < SC_LC; ++l) {
    float a = bdte;
#pragma unroll
    for (int r = 0; r < 12; ++r) a += dtlS[l * 12 + r] * wdtS[r * 128 + t];
    dts[l * 128 + t] = softplusf(a);
  }
  const float Dse = Dskip[e];

  float xA[SC_T], zA[SC_T], xB[SC_T], zB[SC_T];
  auto LOADA = [&](int tt) {
#pragma unroll
    for (int j = 0; j < SC_T; ++j) {
      const size_t r = (size_t)(rowbase + tt * SC_T + j);
      xA[j] = (float)xi[r * 384 + e];
      zA[j] = xz[r * 768 + 384 + e];
    }
  };
  auto LOADB = [&](int tt) {
#pragma unroll
    for (int j = 0; j < SC_T; ++j) {
      const size_t r = (size_t)(rowbase + tt * SC_T + j);
      xB[j] = (float)xi[r * 384 + e];
      zB[j] = xz[r * 768 + 384 + e];
    }
  };
  auto COMP = [&](const float (&x8)[SC_T], const float (&z8)[SC_T], int tt) {
#pragma unroll
    for (int j = 0; j < SC_T; ++j) {
      const int l = tt * SC_T + j;
      const float dtv = dts[l * 128 + t];
      const float xiv = x8[j];
      const float u = dtv * xiv;
      const float* Brow = &BCs[l * 32];
      const float* Crow = Brow + 16;
      float yv = 0.f;
#pragma unroll
      for (int n = 0; n < 16; ++n) {
        const float a = __builtin_amdgcn_exp2f(dtv * An2[n]);
        h[n] = a * h[n] + u * Brow[n];
        yv += h[n] * Crow[n];
      }
      y[(size_t)(rowbase + l) * 384 + e] = (__bf16)((yv + Dse * xiv) * siluf(z8[j]));
    }
  };

  LOADA(0);
#pragma unroll
  for (int tt = 0; tt < SC_TN; ++tt) {
    if (tt & 1) { if (tt + 1 < SC_TN) LOADA(tt + 1); COMP(xB, zB, tt); }
    else        { if (tt + 1 < SC_TN) LOADB(tt + 1); COMP(xA, zA, tt); }
  }
}

extern "C" void kernel_launch(void* const* d_in, const int* in_sizes, int n_in,
                              void* d_out, int out_size, void* d_ws, size_t ws_size,
                              hipStream_t stream)
{
  const float* x    = (const float*)d_in[0];
  const float* pw   = (const float*)d_in[1];
  const float* pb   = (const float*)d_in[2];
  const float* bng  = (const float*)d_in[3];
  const float* bnb  = (const float*)d_in[4];
  const float* bnm  = (const float*)d_in[5];
  const float* bnv  = (const float*)d_in[6];
  const float* lng  = (const float*)d_in[7];
  const float* lnb  = (const float*)d_in[8];
  const float* Win  = (const float*)d_in[9];
  const float* b_in = (const float*)d_in[10];
  const float* cw   = (const float*)d_in[11];
  const float* cb   = (const float*)d_in[12];
  const float* Wx   = (const float*)d_in[13];
  const float* Wdt  = (const float*)d_in[14];
  const float* bdt  = (const float*)d_in[15];
  const float* Alog = (const float*)d_in[16];
  const float* Dsk  = (const float*)d_in[17];
  const float* Wout = (const float*)d_in[18];
  const float* bout = (const float*)d_in[19];

  float* wsf = (float*)d_ws;
  float* v    = wsf;                     // 1204224
  float* xz   = v + 1204224;             // 4816896
  float* dtlb = xz + 4816896;            // 75264
  float* bcb  = dtlb + 75264;            // 200704
  float* Sb   = bcb + 200704;            // 2752512 (NC up to 224)
  float* Pb   = Sb + 2752512;            // 2752512
  __bf16* xiB = (__bf16*)(Pb + 2752512); // 2408448 bf16
  __bf16* yB  = (__bf16*)(Pb + 2752512 + 1204224);   // 2408448 bf16
  __bf16* Wb  = (__bf16*)(Pb + 2752512 + 2408448);   // 714240 bf16

  float* out0 = (float*)d_out;
  float* out1 = out0 + 301056;

  k_proj_wcvt<<<3084, 256, 0, stream>>>(x, pw, pb, bng, bnb, bnm, bnv, v,
                                        Win, Wout, Wx, Wb);

  for (int i = 0; i < 3; ++i) {
    const int big = (i < 2) ? 1 : 0;
    const int Lseq = big ? 3136 : 784;
    const int M = 2 * Lseq;
    const int NC = Lseq / SC_LC;     // 224 big, 56 small
    const int MB = (M + 63) / 64;    // 98 big, 25 small
    const float* lng_i = lng + i * 192;
    const float* lnb_i = lnb + i * 192;
    const float* bin_i = b_in + i * 768;
    const float* cw_i  = cw + i * 384 * 4;
    const float* cb_i  = cb + i * 384;
    const float* Wdt_i = Wdt + i * 384 * 12;
    const float* bdt_i = bdt + i * 384;
    const float* Al_i  = Alog + i * 384 * 16;
    const float* Ds_i  = Dsk + i * 384;
    const float* bo_i  = bout + i * 192;
    const __bf16* Winb_i  = Wb + i * 147456;
    const __bf16* Woutb_i = Wb + 442368 + i * 73728;
    const __bf16* Wxb_i   = Wb + 663552 + i * 16896;

    // xz = LN(src) @ Win^T + b_in  (layer 2: src = maxpool2(v), fused in staging)
    if (big)
      k_gemm<2, 2, EPI_XZ><<<dim3(MB, 6), 256, 0, stream>>>(
          v, Winb_i, bin_i, xz, M, 192, 768,
          nullptr, nullptr, nullptr, lng_i, lnb_i, Lseq);
    else
      k_gemm<3, 2, EPI_XZ><<<dim3(MB, 6), 256, 0, stream>>>(
          v, Winb_i, bin_i, xz, M, 192, 768,
          nullptr, nullptr, nullptr, lng_i, lnb_i, Lseq);
    // depthwise conv + silu -> xiB bf16
    k_conv<<<(M * 384 / 8 + 255) / 256, 256, 0, stream>>>(
        xz, xiB, cw_i, cb_i, Lseq, M * 384 / 8);
    // proj (44 cols): writes dtl (M x 12) + bc (M x 32)
    k_gemm<1, 1, EPI_G2><<<dim3(MB, 1), 256, 0, stream>>>(
        xiB, Wxb_i, nullptr, nullptr, M, 384, 44,
        dtlb, bcb, nullptr, nullptr, nullptr, Lseq);
    k_scan1<<<dim3(2 * NC, 3), 128, 0, stream>>>(
        dtlb, xiB, bcb, Wdt_i, bdt_i, Al_i, Pb, Sb, Lseq, NC);
    k_carry<<<48, 256, 0, stream>>>(Pb, Sb, NC);
    k_scan2<<<dim3(2 * NC, 3), 128, 0, stream>>>(
        dtlb, xiB, bcb, xz, Wdt_i, bdt_i, Al_i, Ds_i, Sb, yB, Lseq, NC);
    if (i == 0)
      k_gemm<1, 1, EPI_RES><<<dim3(MB, 3), 256, 0, stream>>>(
          yB, Woutb_i, bo_i, v, M, 384, 192,
          nullptr, nullptr, nullptr, nullptr, nullptr, Lseq);
    else if (i == 1)
      k_gemm<1, 1, EPI_RES_SKIP><<<dim3(MB, 3), 256, 0, stream>>>(
          yB, Woutb_i, bo_i, v, M, 384, 192,
          nullptr, nullptr, out1, nullptr, nullptr, Lseq);
    else
      k_gemm<1, 1, EPI_OUT2><<<dim3(MB, 3), 256, 0, stream>>>(
          yB, Woutb_i, bo_i, v, M, 384, 192,
          nullptr, nullptr, out0, nullptr, nullptr, Lseq);
  }
}